// Round 5
// baseline (236.915 us; speedup 1.0000x reference)
//
#include <hip/hip_runtime.h>
#include <hip/hip_bf16.h>
#include <hip/hip_fp16.h>
#include <math.h>

#define NB 64
#define CC 512
#define LL 256
#define STRD 72   // halves per LDS row (64 payload + 8 pad)

typedef __attribute__((ext_vector_type(4))) float floatx4;
typedef __attribute__((ext_vector_type(8))) short short8;

static __device__ __forceinline__ unsigned f2bf2(float x, float y) {
    __hip_bfloat162 h = __float22bfloat162_rn(make_float2(x, y));
    union { __hip_bfloat162 h; unsigned u; } c; c.h = h;
    return c.u;   // low 16 = x, high 16 = y
}
static __device__ __forceinline__ unsigned f2h(float x) {
    __half h = __float2half_rn(x);
    union { __half h; unsigned short u; } c; c.h = h;
    return (unsigned)c.u;
}
static __device__ __forceinline__ float h2f(unsigned u) {
    union { unsigned short u; __half h; } c; c.u = (unsigned short)u;
    return __half2float(c.h);
}

// ---------------- Kernel 1: fused compact + norms + dual Gram + distances ----------------
// Per (batch, upper-tri 128x128 tile): ballot-compact positive rows, stage bf16 rows to
// LDS (inline squared-norm partials), MFMA S-Gram then T-Gram, derive ds/dt, write
// per-block partial distance sums to fixed slots, store packed (half ds, half dt).
__global__ __launch_bounds__(256) void dist_kernel(
    const float* __restrict__ S, const float* __restrict__ T,
    const int* __restrict__ targets,
    float* __restrict__ psumS, float* __restrict__ psumT,
    int* __restrict__ npos_ws, unsigned* __restrict__ D,
    float* __restrict__ out)
{
    const int b = blockIdx.x;
    const int n = b & (NB - 1);
    int tI = 0, rem = b >> 6;                 // linear 0..9 -> upper-tri (tI,tJ) of 4x4
    while (rem >= 4 - tI) { rem -= 4 - tI; ++tI; }
    const int tJ = tI + rem;
    const bool diag = (tI == tJ);

    __shared__ int s_idx[CC];
    __shared__ int s_cnt[8], s_off[8];
    __shared__ int s_npS;
    __shared__ __align__(16) unsigned short lds[256 * STRD];   // 36 KB
    __shared__ float s_norm[256];
    __shared__ float redA[4], redB[4];

    const int tid = threadIdx.x;
    const int w = tid >> 6, lane = tid & 63;

    // ---- deterministic ballot compaction (ascending index order) ----
    const int* tg = targets + n * CC;
    const bool p0 = tg[tid] != 0;
    const bool p1 = tg[tid + 256] != 0;
    const unsigned long long m0 = __ballot(p0);
    const unsigned long long m1 = __ballot(p1);
    if (lane == 0) { s_cnt[w] = __popcll(m0); s_cnt[4 + w] = __popcll(m1); }
    __syncthreads();
    if (tid == 0) {
        int a = 0;
        for (int i = 0; i < 8; ++i) { s_off[i] = a; a += s_cnt[i]; }
        s_npS = a;
    }
    __syncthreads();
    const unsigned long long below = (1ull << lane) - 1ull;
    if (p0) s_idx[s_off[w] + __popcll(m0 & below)] = tid;
    if (p1) s_idx[s_off[4 + w] + __popcll(m1 & below)] = tid + 256;
    __syncthreads();
    const int np = s_npS;

    if (b == 0 && tid == 0) out[0] = 0.0f;            // K2 runs after K1: safe
    if ((b >> 6) == 0 && tid == 0) npos_ws[n] = np;

    const bool work = (np >= 2) && (tI * 128 < np) && (tJ * 128 < np);

    const int g4 = lane >> 4;                 // staging: row subgroup
    const int c16 = lane & 15;                // staging: 16B chunk within row
    const int m16 = lane & 15, quad = lane >> 4;
    const int qi = w >> 1, qj = w & 1;        // this wave's 64x64 quadrant
    const bool stager = diag ? (w < 2) : true;
    const int wb = w * 64;
    const int Bbase = diag ? 0 : 128;

    float t0 = 0.0f, t1 = 0.0f;
    if (work) {
        unsigned dpk[32];                     // ds packed fp16 (64 values)
        floatx4 acc[16];
        float l0 = 0.0f, l1 = 0.0f;
        unsigned* Dn = D + ((size_t)b << 14); // 128x128 packed entries

        for (int pass = 0; pass < 2; ++pass) {
            const float* P = (pass ? T : S) + (size_t)n * CC * LL;
            float nprt[16];
            #pragma unroll
            for (int i = 0; i < 16; ++i) nprt[i] = 0.0f;
            #pragma unroll
            for (int i = 0; i < 16; ++i) {
                acc[i][0] = 0.0f; acc[i][1] = 0.0f; acc[i][2] = 0.0f; acc[i][3] = 0.0f;
            }

            for (int kk = 0; kk < 4; ++kk) {
                if (stager) {
                    #pragma unroll
                    for (int i = 0; i < 16; ++i) {
                        const int rb = wb + 4 * i + g4;
                        const int gk = (rb < 128) ? (tI * 128 + rb) : (tJ * 128 + rb - 128);
                        const int ri = s_idx[(gk < np) ? gk : 0];
                        const float4 v = *(const float4*)(P + (size_t)ri * LL + kk * 64 + c16 * 4);
                        nprt[i] += v.x * v.x + v.y * v.y + v.z * v.z + v.w * v.w;
                        *(uint2*)&lds[rb * STRD + c16 * 4] =
                            make_uint2(f2bf2(v.x, v.y), f2bf2(v.z, v.w));
                    }
                }
                __syncthreads();
                #pragma unroll
                for (int k2 = 0; k2 < 2; ++k2) {
                    const int ko = k2 * 32 + quad * 8;
                    short8 af[4], bf[4];
                    #pragma unroll
                    for (int rt = 0; rt < 4; ++rt)
                        af[rt] = *(const short8*)&lds[(qi * 64 + rt * 16 + m16) * STRD + ko];
                    #pragma unroll
                    for (int ct = 0; ct < 4; ++ct)
                        bf[ct] = *(const short8*)&lds[(Bbase + qj * 64 + ct * 16 + m16) * STRD + ko];
                    #pragma unroll
                    for (int ct = 0; ct < 4; ++ct)
                        #pragma unroll
                        for (int rt = 0; rt < 4; ++rt)
                            acc[ct * 4 + rt] = __builtin_amdgcn_mfma_f32_16x16x32_bf16(
                                af[rt], bf[ct], acc[ct * 4 + rt], 0, 0, 0);
                }
                __syncthreads();
            }

            // inline norms: 16 lanes share each staged row
            if (stager) {
                #pragma unroll
                for (int i = 0; i < 16; ++i) {
                    float v = nprt[i];
                    v += __shfl_xor(v, 1); v += __shfl_xor(v, 2);
                    v += __shfl_xor(v, 4); v += __shfl_xor(v, 8);
                    if (c16 == 0) s_norm[wb + 4 * i + g4] = v;
                }
            }
            __syncthreads();

            // distances; C/D layout: col=lane&15, row=quad*4+reg
            #pragma unroll
            for (int ct = 0; ct < 4; ++ct) {
                const int colL = qj * 64 + ct * 16 + m16;
                const float nB = s_norm[Bbase + colL];
                const int gj = tJ * 128 + colL;
                #pragma unroll
                for (int rt = 0; rt < 4; ++rt) {
                    float dv[4];
                    #pragma unroll
                    for (int r = 0; r < 4; ++r) {
                        const int rowL = qi * 64 + rt * 16 + quad * 4 + r;
                        const int gi = tI * 128 + rowL;
                        const float d = sqrtf(fmaxf(s_norm[rowL] + nB - 2.0f * acc[ct * 4 + rt][r], 1e-12f));
                        const bool valid = (gi < np) && (gj < np) && (gi != gj);
                        if (valid) { if (pass == 0) l0 += d; else l1 += d; }
                        dv[r] = d;
                    }
                    const int ti = ct * 4 + rt;
                    if (pass == 0) {
                        dpk[ti * 2 + 0] = f2h(dv[0]) | (f2h(dv[1]) << 16);
                        dpk[ti * 2 + 1] = f2h(dv[2]) | (f2h(dv[3]) << 16);
                    } else {
                        #pragma unroll
                        for (int r = 0; r < 4; ++r) {
                            const int rowL = qi * 64 + rt * 16 + quad * 4 + r;
                            const unsigned u = dpk[ti * 2 + (r >> 1)];
                            const unsigned dsb = (r & 1) ? (u >> 16) : (u & 0xffffu);
                            Dn[rowL * 128 + colL] = dsb | (f2h(dv[r]) << 16);
                        }
                    }
                }
            }
            __syncthreads();
        }

        #pragma unroll
        for (int o = 32; o; o >>= 1) { l0 += __shfl_down(l0, o); l1 += __shfl_down(l1, o); }
        if (lane == 0) { redA[w] = l0; redB[w] = l1; }
        __syncthreads();
        if (tid == 0) {
            const float wgt = diag ? 1.0f : 2.0f;   // off-diag tiles mirror-counted
            t0 = wgt * (redA[0] + redA[1] + redA[2] + redA[3]);
            t1 = wgt * (redB[0] + redB[1] + redB[2] + redB[3]);
        }
    }
    if (tid == 0) { psumS[b] = t0; psumT[b] = t1; }   // fixed slots: no atomics, no init
}

// ---------------- Kernel 2: streaming Huber over packed (ds, dt) ----------------
__global__ __launch_bounds__(256) void huber_kernel(
    const unsigned* __restrict__ D, const int* __restrict__ npos,
    const float* __restrict__ psumS, const float* __restrict__ psumT,
    float* __restrict__ out)
{
    const int b = blockIdx.x;
    const int n = b & (NB - 1);
    int tI = 0, rem = b >> 6;
    while (rem >= 4 - tI) { rem -= 4 - tI; ++tI; }
    const int tJ = tI + rem;

    const int np = npos[n];
    if (np < 2) return;
    if (tI * 128 >= np || tJ * 128 >= np) return;

    float ss = 0.0f, st = 0.0f;
    #pragma unroll
    for (int t = 0; t < 10; ++t) { ss += psumS[t * 64 + n]; st += psumT[t * 64 + n]; }
    const float cnt = (float)np * (float)(np - 1);
    const float inv_ms = cnt / ss;
    const float inv_mt = cnt / st;

    const uint4* Dn = (const uint4*)(D + ((size_t)b << 14));
    const int tid = threadIdx.x;

    float h = 0.0f;
    #pragma unroll
    for (int it = 0; it < 16; ++it) {
        const int e4 = it * 256 + tid;        // uint4 index; element = e4*4
        const uint4 v = Dn[e4];
        const unsigned vv[4] = { v.x, v.y, v.z, v.w };
        const int e0 = e4 * 4;
        #pragma unroll
        for (int k = 0; k < 4; ++k) {
            const int e = e0 + k;
            const int gi = tI * 128 + (e >> 7);
            const int gj = tJ * 128 + (e & 127);
            if (gi < np && gj < np && gi != gj) {
                const float ds = h2f(vv[k] & 0xffffu);
                const float dt = h2f(vv[k] >> 16);
                const float diff = ds * inv_ms - dt * inv_mt;
                const float ad = fabsf(diff);
                h += (ad < 1.0f) ? 0.5f * diff * diff : ad - 0.5f;
            }
        }
    }

    #pragma unroll
    for (int o = 32; o; o >>= 1) h += __shfl_down(h, o);
    __shared__ float red[4];
    const int w = tid >> 6, lane = tid & 63;
    if (lane == 0) red[w] = h;
    __syncthreads();
    if (tid == 0) {
        const float wgt = (tI == tJ) ? 1.0f : 2.0f;
        atomicAdd(out, wgt * (red[0] + red[1] + red[2] + red[3]) / (float)np);
    }
}

extern "C" void kernel_launch(void* const* d_in, const int* in_sizes, int n_in,
                              void* d_out, int out_size, void* d_ws, size_t ws_size,
                              hipStream_t stream) {
    const float* S = (const float*)d_in[0];
    const float* T = (const float*)d_in[1];
    const int* targets = (const int*)d_in[2];
    float* out = (float*)d_out;

    float* psumS = (float*)d_ws;             // 640
    float* psumT = psumS + 640;              // 640
    int* npos_ws = (int*)(psumT + 640);      // 64
    size_t off = ((size_t)((char*)(npos_ws + 64) - (char*)d_ws) + 255) & ~(size_t)255;
    unsigned* D = (unsigned*)((char*)d_ws + off);   // 640 * 16384 uint = 41.9 MB

    dist_kernel<<<640, 256, 0, stream>>>(S, T, targets, psumS, psumT, npos_ws, D, out);
    huber_kernel<<<640, 256, 0, stream>>>(D, npos_ws, psumS, psumT, out);
}

// Round 6
// 136.491 us; speedup vs baseline: 1.7358x; 1.7358x over previous
//
#include <hip/hip_runtime.h>
#include <hip/hip_bf16.h>
#include <hip/hip_fp16.h>
#include <math.h>

#define NB 64
#define CC 512
#define LL 256

typedef __attribute__((ext_vector_type(4))) float floatx4;
typedef __attribute__((ext_vector_type(8))) short short8;

static __device__ __forceinline__ unsigned f2bf2(float x, float y) {
    __hip_bfloat162 h = __float22bfloat162_rn(make_float2(x, y));
    union { __hip_bfloat162 h; unsigned u; } c; c.h = h;
    return c.u;   // low 16 = x, high 16 = y
}
static __device__ __forceinline__ unsigned f2h(float x) {
    __half h = __float2half_rn(x);
    union { __half h; unsigned short u; } c; c.h = h;
    return (unsigned)c.u;
}
static __device__ __forceinline__ float h2f(unsigned u) {
    union { unsigned short u; __half h; } c; c.u = (unsigned short)u;
    return __half2float(c.h);
}

// ---------------- Kernel 1: fused compact + inline norms + dual Gram + distances ----
// 64x64 tiles (36 upper-tri per batch, 2304 blocks): ballot-compact, stage bf16 rows
// to LDS via register prefetch (row norms accumulated inline), MFMA S- and T-Gram
// simultaneously, derive ds/dt, store packed fp16 pairs, psums to fixed slots.
__global__ __launch_bounds__(256) void dist_kernel(
    const float* __restrict__ S, const float* __restrict__ T,
    const int* __restrict__ targets,
    float* __restrict__ psumS, float* __restrict__ psumT,
    int* __restrict__ npos_ws, unsigned* __restrict__ D,
    float* __restrict__ out)
{
    const int lin = blockIdx.x, n = blockIdx.y;
    int tI = 0, rem = lin;                    // linear -> upper-tri (tI,tJ) of 8x8
    while (rem >= 8 - tI) { rem -= 8 - tI; ++tI; }
    const int tJ = tI + rem;
    const bool diag = (tI == tJ);

    __shared__ int s_idx[CC];
    __shared__ int s_cnt[8], s_off[8];
    __shared__ int s_npS;
    __shared__ __align__(16) unsigned short lds[4][64][40];   // 20480 B
    __shared__ float s_norm[4][64];
    __shared__ float redA[4], redB[4];

    const int tid = threadIdx.x;
    const int w = tid >> 6, lane = tid & 63;

    // ---- deterministic ballot compaction (ascending index order) ----
    const int* tg = targets + n * CC;
    const bool p0 = tg[tid] != 0;
    const bool p1 = tg[tid + 256] != 0;
    const unsigned long long m0 = __ballot(p0);
    const unsigned long long m1 = __ballot(p1);
    if (lane == 0) { s_cnt[w] = __popcll(m0); s_cnt[4 + w] = __popcll(m1); }
    __syncthreads();
    if (tid == 0) {
        int a = 0;
        for (int i = 0; i < 8; ++i) { s_off[i] = a; a += s_cnt[i]; }
        s_npS = a;
    }
    __syncthreads();
    const unsigned long long below = (1ull << lane) - 1ull;
    if (p0) s_idx[s_off[w] + __popcll(m0 & below)] = tid;
    if (p1) s_idx[s_off[4 + w] + __popcll(m1 & below)] = tid + 256;
    __syncthreads();
    const int np = s_npS;

    if (tid == 0 && lin == 0) {
        npos_ws[n] = np;
        if (n == 0) out[0] = 0.0f;            // K2 strictly follows K1: safe
    }

    const bool work = (np >= 2) && (tI * 64 < np) && (tJ * 64 < np);

    float t0 = 0.0f, t1 = 0.0f;
    if (work) {
        // wave w stages buffer w: 0=S-A, 1=S-B, 2=T-A, 3=T-B (diag: B aliases A)
        const bool stager = (!diag) || ((w & 1) == 0);
        const char* Pbase = (const char*)(((w >> 1) ? T : S) + (size_t)n * CC * LL);
        const int tileBase = ((w & 1) ? tJ : tI) * 64;
        const int r8 = lane >> 3, c8 = lane & 7;   // 8 lanes/row, 128 B per row-chunk
        unsigned off_[8];
        #pragma unroll
        for (int i = 0; i < 8; ++i) {
            const int gk = tileBase + r8 + 8 * i;
            const int row = s_idx[(gk < np) ? gk : 0];
            off_[i] = (unsigned)(row * LL * 4 + c8 * 16);
        }

        float4 pre[8];
        float nprt[8];
        #pragma unroll
        for (int i = 0; i < 8; ++i) nprt[i] = 0.0f;
        if (stager) {
            #pragma unroll
            for (int i = 0; i < 8; ++i) pre[i] = *(const float4*)(Pbase + off_[i]);
        }

        const int m16 = lane & 15, quad = lane >> 4;
        const int bufB = diag ? 0 : 1;
        const int wrow = w * 16;

        floatx4 accS[4], accT[4];
        #pragma unroll
        for (int c = 0; c < 4; ++c) {
            accS[c][0] = 0; accS[c][1] = 0; accS[c][2] = 0; accS[c][3] = 0;
            accT[c][0] = 0; accT[c][1] = 0; accT[c][2] = 0; accT[c][3] = 0;
        }

        for (int kk = 0; kk < 8; ++kk) {
            __syncthreads();   // prior chunk's LDS reads complete
            if (stager) {
                #pragma unroll
                for (int i = 0; i < 8; ++i) {
                    nprt[i] += pre[i].x * pre[i].x + pre[i].y * pre[i].y +
                               pre[i].z * pre[i].z + pre[i].w * pre[i].w;
                    *(uint2*)&lds[w][r8 + 8 * i][c8 * 4] =
                        make_uint2(f2bf2(pre[i].x, pre[i].y), f2bf2(pre[i].z, pre[i].w));
                }
            }
            __syncthreads();
            if (stager && kk < 7) {            // prefetch next chunk during MFMA
                #pragma unroll
                for (int i = 0; i < 8; ++i)
                    pre[i] = *(const float4*)(Pbase + off_[i] + (kk + 1) * 128);
            }
            const int aoff = (wrow + m16) * 40 + quad * 8;
            const short8 a_s = *(const short8*)(&lds[0][0][0] + aoff);
            const short8 a_t = *(const short8*)(&lds[2][0][0] + aoff);
            #pragma unroll
            for (int c = 0; c < 4; ++c) {
                const int boff = (c * 16 + m16) * 40 + quad * 8;
                const short8 b_s = *(const short8*)(&lds[bufB][0][0] + boff);
                const short8 b_t = *(const short8*)(&lds[2 + bufB][0][0] + boff);
                accS[c] = __builtin_amdgcn_mfma_f32_16x16x32_bf16(a_s, b_s, accS[c], 0, 0, 0);
                accT[c] = __builtin_amdgcn_mfma_f32_16x16x32_bf16(a_t, b_t, accT[c], 0, 0, 0);
            }
        }

        // ---- inline norms: reduce the 8 lanes (c8) sharing each staged row ----
        if (stager) {
            #pragma unroll
            for (int i = 0; i < 8; ++i) {
                float v = nprt[i];
                v += __shfl_xor(v, 1); v += __shfl_xor(v, 2); v += __shfl_xor(v, 4);
                if (c8 == 0) s_norm[w][r8 + 8 * i] = v;
            }
        }
        __syncthreads();

        // ---- distances; C/D layout: col=lane&15, row=quad*4+reg ----
        unsigned* Dn = D + (((size_t)n * 36 + lin) << 12);   // 64x64 entries
        float l0 = 0.0f, l1 = 0.0f;
        #pragma unroll
        for (int c = 0; c < 4; ++c) {
            const int colL = c * 16 + m16;
            const int gj = tJ * 64 + colL;
            const float nBs = s_norm[bufB][colL];
            const float nBt = s_norm[2 + bufB][colL];
            #pragma unroll
            for (int r = 0; r < 4; ++r) {
                const int rowL = wrow + quad * 4 + r;
                const int gi = tI * 64 + rowL;
                const float ds = sqrtf(fmaxf(s_norm[0][rowL] + nBs - 2.0f * accS[c][r], 1e-12f));
                const float dt = sqrtf(fmaxf(s_norm[2][rowL] + nBt - 2.0f * accT[c][r], 1e-12f));
                if (gi < np && gj < np && gi != gj) { l0 += ds; l1 += dt; }
                Dn[rowL * 64 + colL] = f2h(ds) | (f2h(dt) << 16);
            }
        }

        #pragma unroll
        for (int o = 32; o; o >>= 1) { l0 += __shfl_down(l0, o); l1 += __shfl_down(l1, o); }
        if (lane == 0) { redA[w] = l0; redB[w] = l1; }
        __syncthreads();
        if (tid == 0) {
            const float wgt = diag ? 1.0f : 2.0f;   // off-diag tiles mirror-counted
            t0 = wgt * (redA[0] + redA[1] + redA[2] + redA[3]);
            t1 = wgt * (redB[0] + redB[1] + redB[2] + redB[3]);
        }
    }
    if (tid == 0) { psumS[lin * 64 + n] = t0; psumT[lin * 64 + n] = t1; }
}

// ---------------- Kernel 2: streaming Huber over packed (ds, dt) ----------------
__global__ __launch_bounds__(256) void huber_kernel(
    const unsigned* __restrict__ D, const int* __restrict__ npos,
    const float* __restrict__ psumS, const float* __restrict__ psumT,
    float* __restrict__ out)
{
    const int lin = blockIdx.x, n = blockIdx.y;
    int tI = 0, rem = lin;
    while (rem >= 8 - tI) { rem -= 8 - tI; ++tI; }
    const int tJ = tI + rem;

    const int np = npos[n];
    if (np < 2) return;
    if (tI * 64 >= np || tJ * 64 >= np) return;

    float ss = 0.0f, st = 0.0f;
    #pragma unroll
    for (int t = 0; t < 36; ++t) { ss += psumS[t * 64 + n]; st += psumT[t * 64 + n]; }
    const float cnt = (float)np * (float)(np - 1);
    const float inv_ms = cnt / ss;
    const float inv_mt = cnt / st;

    const uint4* Dn = (const uint4*)(D + (((size_t)n * 36 + lin) << 12));
    const int tid = threadIdx.x;

    float h = 0.0f;
    #pragma unroll
    for (int it = 0; it < 4; ++it) {
        const int e4 = it * 256 + tid;        // uint4 index; element = e4*4
        const uint4 v = Dn[e4];
        const unsigned vv[4] = { v.x, v.y, v.z, v.w };
        const int e0 = e4 * 4;
        #pragma unroll
        for (int k = 0; k < 4; ++k) {
            const int e = e0 + k;
            const int gi = tI * 64 + (e >> 6);
            const int gj = tJ * 64 + (e & 63);
            if (gi < np && gj < np && gi != gj) {
                const float ds = h2f(vv[k] & 0xffffu);
                const float dt = h2f(vv[k] >> 16);
                const float diff = ds * inv_ms - dt * inv_mt;
                const float ad = fabsf(diff);
                h += (ad < 1.0f) ? 0.5f * diff * diff : ad - 0.5f;
            }
        }
    }

    #pragma unroll
    for (int o = 32; o; o >>= 1) h += __shfl_down(h, o);
    __shared__ float red[4];
    const int w = tid >> 6, lane = tid & 63;
    if (lane == 0) red[w] = h;
    __syncthreads();
    if (tid == 0) {
        const float wgt = (tI == tJ) ? 1.0f : 2.0f;
        atomicAdd(out, wgt * (red[0] + red[1] + red[2] + red[3]) / (float)np);
    }
}

extern "C" void kernel_launch(void* const* d_in, const int* in_sizes, int n_in,
                              void* d_out, int out_size, void* d_ws, size_t ws_size,
                              hipStream_t stream) {
    const float* S = (const float*)d_in[0];
    const float* T = (const float*)d_in[1];
    const int* targets = (const int*)d_in[2];
    float* out = (float*)d_out;

    float* psumS = (float*)d_ws;             // 2304
    float* psumT = psumS + 2304;             // 2304
    int* npos_ws = (int*)(psumT + 2304);     // 64
    size_t off = ((size_t)((char*)(npos_ws + 64) - (char*)d_ws) + 255) & ~(size_t)255;
    unsigned* D = (unsigned*)((char*)d_ws + off);   // 64*36*4096 uint = 37.7 MB

    dim3 grid(36, NB);
    dist_kernel<<<grid, 256, 0, stream>>>(S, T, targets, psumS, psumT, npos_ws, D, out);
    huber_kernel<<<grid, 256, 0, stream>>>(D, npos_ws, psumS, psumT, out);
}